// Round 4
// baseline (138.614 us; speedup 1.0000x reference)
//
#include <hip/hip_runtime.h>
#include <hip/hip_bf16.h>

// Sizes (fixed by the problem)
#define E_CNT 131072
#define NP_CNT 65536
#define D_P 80
#define D_C 48
#define D_ADD 16
#define K1 1152   // 144*8
#define K2 512    // 64*8

typedef _Float16 f16x8 __attribute__((ext_vector_type(8)));
typedef _Float16 f16x2 __attribute__((ext_vector_type(2)));
typedef float f32x4 __attribute__((ext_vector_type(4)));

union F16x8U { f16x2 h2[4]; f16x8 v8; };

__device__ __forceinline__ float silu_f(float x){
  return x / (1.0f + __expf(-x));
}
__device__ __forceinline__ f16x2 pkrtz(float a, float b){
  return __builtin_bit_cast(f16x2, __builtin_amdgcn_cvt_pkrtz(a, b));
}

// ---------------------------------------------------------------------------
// Kernel 1: W1 [144][8][64] f32 -> Wt1 [64][1152] f16 ; W2 -> Wt2 [64][512]
// Wt[h][k] = Wflat[k][h]
// ---------------------------------------------------------------------------
__global__ void prep_w_kernel(const float* __restrict__ W1, const float* __restrict__ W2,
                              _Float16* __restrict__ wt1, _Float16* __restrict__ wt2){
  int id = blockIdx.x * 256 + threadIdx.x;
  if (id < 64 * K1){
    int h = id / K1;
    int k = id - h * K1;
    wt1[id] = (_Float16)W1[k * 64 + h];
  } else {
    int id2 = id - 64 * K1;
    int h = id2 / K2;
    int k = id2 - h * K2;
    wt2[id2] = (_Float16)W2[k * 64 + h];
  }
}

// ---------------------------------------------------------------------------
// Kernel 2: out[n, 0:80] = x_p[n]; out[n, 80:144] = 0
// ---------------------------------------------------------------------------
__global__ void init_out_kernel(const float4* __restrict__ xp4, float4* __restrict__ out4){
  int i4 = blockIdx.x * 256 + threadIdx.x;
  int row = i4 / 36;
  int jq = i4 - row * 36;
  float4 z = make_float4(0.f, 0.f, 0.f, 0.f);
  out4[i4] = (jq < 20) ? xp4[row * 20 + jq] : z;
}

// ---------------------------------------------------------------------------
// Register-A GEMM: out[e,h] = sum_k xa[e,k]*Wt[h][k], xa[e,f*8+g]=x[e,f]*a[e,g].
// A-frag of mfma_16x16x32_f16 for lane l = x[e=l&15, f=ks*4+(l>>4)] * a[e, 0..7]
// -> built in registers (1 pkrtz + 4 pk_mul), NO LDS for A, NO barriers in loop.
// W persistent in padded dynamic LDS ([64][KTOT+8] f16; quad stride 1 mod 8 =>
// conflict-free b128 reads). 512 thr = 8 waves = 4(edge quarters) x 2(h halves);
// wave tile 128 edges x 32 h; grid = E/512 = 256 = #CUs, 1 block/CU.
// x gathered per-lane from global with depth-4 register prefetch (full unroll).
// ---------------------------------------------------------------------------
template<int KTOT, bool SECOND>
__global__ __launch_bounds__(512, 2) void msg_gemm_kernel(
    const float* __restrict__ x_p, const float* __restrict__ x_c,
    const int* __restrict__ eidx, const float* __restrict__ ea,
    const float* __restrict__ addf,
    const _Float16* __restrict__ wt, const float* __restrict__ bias,
    const unsigned short* __restrict__ m1in,
    _Float16* __restrict__ m1out,
    float* __restrict__ out)
{
  extern __shared__ _Float16 s_w[];     // [64][KTOT+8]
  __shared__ int s_dst[512];
  constexpr int ROW = KTOT + 8;         // padded row (f16 units): +16B
  constexpr int NKS = KTOT / 32;        // k-steps of 32
  constexpr int KCH = KTOT / 8;         // 16B chunks per W row

  const int t    = threadIdx.x;
  const int lane = t & 63;
  const int wv   = t >> 6;              // 0..7
  const int wm   = wv >> 1;             // edge quarter 0..3
  const int wn   = wv & 1;              // h half 0..1
  const int l15  = lane & 15;
  const int q    = lane >> 4;           // 0..3

  // ---- stage full W into padded LDS (once)
  for (int i = t; i < 64 * KCH; i += 512){
    int h = i / KCH, p = i - h * KCH;
    *reinterpret_cast<uint4*>(&s_w[h * ROW + p * 8]) =
        *reinterpret_cast<const uint4*>(wt + h * KTOT + p * 8);
  }
  if constexpr (SECOND) s_dst[t] = eidx[E_CNT + blockIdx.x * 512 + t];

  const int ebase = blockIdx.x * 512 + wm * 128;

  // ---- per-mt gather bases + edge_attr f16 pairs
  int iP[8], iC[8], iA[8], iM[8];
  f16x2 apk[8][4];
  #pragma unroll
  for (int mt = 0; mt < 8; ++mt){
    const int e = ebase + mt * 16 + l15;
    if constexpr (!SECOND){
      const int d = eidx[E_CNT + e];
      const int s = eidx[e];
      iP[mt] = d * D_P + q;
      iC[mt] = s * D_C + q;
      iA[mt] = e * D_ADD + q;
      iM[mt] = 0;
    } else {
      iM[mt] = e * 64 + q;
      iP[mt] = iC[mt] = iA[mt] = 0;
    }
    const float4* ap = reinterpret_cast<const float4*>(ea + (size_t)e * 8);
    float4 a0 = ap[0], a1 = ap[1];
    apk[mt][0] = pkrtz(a0.x, a0.y);
    apk[mt][1] = pkrtz(a0.z, a0.w);
    apk[mt][2] = pkrtz(a1.x, a1.y);
    apk[mt][3] = pkrtz(a1.z, a1.w);
  }

  f32x4 acc[8][2];
  #pragma unroll
  for (int mt = 0; mt < 8; ++mt){
    acc[mt][0] = f32x4{0.f,0.f,0.f,0.f};
    acc[mt][1] = f32x4{0.f,0.f,0.f,0.f};
  }

  float    xf[4][8];   // depth-4 prefetch (f32 path, !SECOND)
  unsigned xu[4][8];   // depth-4 prefetch (u16 path, SECOND)

  const int wb = (wn * 32 + l15) * ROW + q * 8;  // B-frag f16-index base (nt=0)

  auto FETCH = [&](int ks, int sl){
    #pragma unroll
    for (int mt = 0; mt < 8; ++mt){
      if constexpr (!SECOND){
        if (ks < 20)      xf[sl][mt] = x_p [iP[mt] + ks * 4];
        else if (ks < 32) xf[sl][mt] = x_c [iC[mt] + (ks - 20) * 4];
        else              xf[sl][mt] = addf[iA[mt] + (ks - 32) * 4];
      } else {
        xu[sl][mt] = m1in[iM[mt] + ks * 4];
      }
    }
  };

  FETCH(0, 0); FETCH(1, 1); FETCH(2, 2); FETCH(3, 3);
  __syncthreads();   // W staged

  #pragma unroll
  for (int ks = 0; ks < NKS; ++ks){
    const int sl = ks & 3;
    f16x8 Bf[2];
    #pragma unroll
    for (int nt = 0; nt < 2; ++nt)
      Bf[nt] = __builtin_bit_cast(f16x8,
          *reinterpret_cast<const uint4*>(&s_w[wb + nt * 16 * ROW + ks * 32]));
    #pragma unroll
    for (int mt = 0; mt < 8; ++mt){
      f16x2 xb;
      if constexpr (!SECOND){
        float xvv = xf[sl][mt];
        xb = pkrtz(xvv, xvv);
      } else {
        unsigned uu = xu[sl][mt];
        xb = __builtin_bit_cast(f16x2, (uu << 16) | uu);
      }
      F16x8U A;
      #pragma unroll
      for (int j = 0; j < 4; ++j) A.h2[j] = xb * apk[mt][j];
      acc[mt][0] = __builtin_amdgcn_mfma_f32_16x16x32_f16(A.v8, Bf[0], acc[mt][0], 0, 0, 0);
      acc[mt][1] = __builtin_amdgcn_mfma_f32_16x16x32_f16(A.v8, Bf[1], acc[mt][1], 0, 0, 0);
    }
    if (ks + 4 < NKS) FETCH(ks + 4, sl);
  }

  // ---- epilogue: +bias, SiLU; C/D: col = l15, row = q*4 + r
  float bv[2];
  bv[0] = bias[wn * 32 + l15];
  bv[1] = bias[wn * 32 + 16 + l15];

  #pragma unroll
  for (int mt = 0; mt < 8; ++mt){
    #pragma unroll
    for (int nt = 0; nt < 2; ++nt){
      #pragma unroll
      for (int r = 0; r < 4; ++r){
        float s = silu_f(acc[mt][nt][r] + bv[nt]);
        const int eo = wm * 128 + mt * 16 + q * 4 + r;   // block-local edge
        const int h  = wn * 32 + nt * 16 + l15;
        if constexpr (!SECOND){
          m1out[(size_t)(blockIdx.x * 512 + eo) * 64 + h] = (_Float16)s;
        } else {
          unsafeAtomicAdd(out + (size_t)s_dst[eo] * 144 + 80 + h, s);
        }
      }
    }
  }
}

extern "C" void kernel_launch(void* const* d_in, const int* in_sizes, int n_in,
                              void* d_out, int out_size, void* d_ws, size_t ws_size,
                              hipStream_t stream){
  const float* x_p  = (const float*)d_in[0];
  const float* x_c  = (const float*)d_in[1];
  const int*   eidx = (const int*)d_in[2];
  const float* ea   = (const float*)d_in[3];
  // d_in[4] = batch (unused)
  const float* addf = (const float*)d_in[5];
  const float* W1   = (const float*)d_in[6];
  const float* b1   = (const float*)d_in[7];
  const float* W2   = (const float*)d_in[8];
  const float* b2   = (const float*)d_in[9];
  float* out = (float*)d_out;

  char* ws = (char*)d_ws;
  _Float16* wt1 = (_Float16*)(ws);             // 147456 B
  _Float16* wt2 = (_Float16*)(ws + 163840);    //  65536 B
  _Float16* m1  = (_Float16*)(ws + 262144);    // 16.78 MB (E*64 f16)

  constexpr int SH1 = 64 * (K1 + 8) * 2;   // 148480 B
  constexpr int SH2 = 64 * (K2 + 8) * 2;   //  66560 B
  hipFuncSetAttribute(reinterpret_cast<const void*>(msg_gemm_kernel<K1, false>),
                      hipFuncAttributeMaxDynamicSharedMemorySize, SH1);
  hipFuncSetAttribute(reinterpret_cast<const void*>(msg_gemm_kernel<K2, true>),
                      hipFuncAttributeMaxDynamicSharedMemorySize, SH2);

  prep_w_kernel<<<(64 * K1 + 64 * K2) / 256, 256, 0, stream>>>(W1, W2, wt1, wt2);
  init_out_kernel<<<(NP_CNT * 36) / 256, 256, 0, stream>>>((const float4*)x_p, (float4*)out);
  msg_gemm_kernel<K1, false><<<E_CNT / 512, 512, SH1, stream>>>(
      x_p, x_c, eidx, ea, addf, wt1, b1, nullptr, m1, nullptr);
  msg_gemm_kernel<K2, true><<<E_CNT / 512, 512, SH2, stream>>>(
      x_p, x_c, eidx, ea, addf, wt2, b2, (const unsigned short*)m1, nullptr, out);
}

// Round 5
// 119.116 us; speedup vs baseline: 1.1637x; 1.1637x over previous
//
#include <hip/hip_runtime.h>
#include <hip/hip_bf16.h>

// Sizes (fixed by the problem)
#define E_CNT 131072
#define NP_CNT 65536
#define D_P 80
#define D_C 48
#define D_ADD 16
#define K1 1152   // 144*8
#define K2 512    // 64*8

typedef _Float16 f16x8 __attribute__((ext_vector_type(8)));
typedef _Float16 f16x2 __attribute__((ext_vector_type(2)));
typedef float f32x4 __attribute__((ext_vector_type(4)));

union F16x8U { f16x2 h2[4]; f16x8 v8; };

__device__ __forceinline__ float silu_f(float x){
  return x / (1.0f + __expf(-x));
}
__device__ __forceinline__ f16x2 pkrtz(float a, float b){
  return __builtin_bit_cast(f16x2, __builtin_amdgcn_cvt_pkrtz(a, b));
}

// ---------------------------------------------------------------------------
// K-permutation: logical k = f*8+g; physical k = ks*32 + q*8 + j.
// We choose f(q,ks) = q*NKS + ks  (NKS = KTOT/32), g = j.  Applied identically
// to A (lane build) and B (pre-transposed W) so the GEMM result is unchanged,
// but lane q's x-gather becomes CONTIGUOUS in f (one float4 per K128 chunk).
// prep_w: Wt[h][ks*32+q*8+j] = W[(q*NKS+ks)*512 + j*64 + h]
// ---------------------------------------------------------------------------
__global__ void prep_w_kernel(const float* __restrict__ W1, const float* __restrict__ W2,
                              _Float16* __restrict__ wt1, _Float16* __restrict__ wt2){
  int id = blockIdx.x * 256 + threadIdx.x;
  if (id < 64 * K1){
    int h = id / K1, k = id - h * K1;
    int ks = k >> 5, rem = k & 31, q = rem >> 3, j = rem & 7;
    wt1[id] = (_Float16)W1[(q * 36 + ks) * 512 + j * 64 + h];
  } else {
    int id2 = id - 64 * K1;
    int h = id2 / K2, k = id2 - h * K2;
    int ks = k >> 5, rem = k & 31, q = rem >> 3, j = rem & 7;
    wt2[id2] = (_Float16)W2[(q * 16 + ks) * 512 + j * 64 + h];
  }
}

// ---------------------------------------------------------------------------
// out[n,0:80] = x_p[n]; out[n,80:144] = 0  (also re-zeros agg each call)
// ---------------------------------------------------------------------------
__global__ void init_out_kernel(const float4* __restrict__ xp4, float4* __restrict__ out4){
  int i4 = blockIdx.x * 256 + threadIdx.x;
  int row = i4 / 36;
  int jq = i4 - row * 36;
  float4 z = make_float4(0.f, 0.f, 0.f, 0.f);
  out4[i4] = (jq < 20) ? xp4[row * 20 + jq] : z;
}

// ---------------------------------------------------------------------------
// Register-A GEMM, chunked-W LDS:
//  - 512 thr = 8 waves = 4 wm x 2 wn; block tile 256 edges x 64 h;
//    wave tile 64 edges x 32 h (mt=4, nt=2). Grid = E/256 = 512, 2 blocks/CU,
//    4 waves/SIMD (launch_bounds 512,4 -> VGPR<=128).
//  - A-frag built in registers: lane(l15,q), step ks: x[e, q*NKS+ks] * a[e,0..7]
//    (1 broadcast + 4 pk_mul). x fetched as ONE float4 per K128-chunk (f map).
//  - W staged per K128-chunk: 16KB, double-buffered, padded rows [64][136]
//    (row=272B => 2-way bank alias only). 1 barrier/chunk; stage loads issued
//    before compute, ds_write after (T14).
// ---------------------------------------------------------------------------
template<int KTOT, bool SECOND>
__global__ __launch_bounds__(512, 4) void msg_gemm_kernel(
    const float* __restrict__ x_p, const float* __restrict__ x_c,
    const int* __restrict__ eidx, const float* __restrict__ ea,
    const float* __restrict__ addf,
    const _Float16* __restrict__ wt, const float* __restrict__ bias,
    const unsigned short* __restrict__ m1in,
    _Float16* __restrict__ m1out,
    float* __restrict__ out)
{
  constexpr int NKS = KTOT / 32;        // k-steps of 32 (36 / 16)
  constexpr int NCH = NKS / 4;          // K128 chunks (9 / 4)
  constexpr int CHROW = 136;            // padded chunk row in f16 (128+8)
  __shared__ _Float16 s_w[2][64 * CHROW];   // 2 x 17 KB
  __shared__ int s_dst[256];

  const int t    = threadIdx.x;
  const int lane = t & 63;
  const int wv   = t >> 6;              // 0..7
  const int wm   = wv >> 1;             // 0..3 edge quarter
  const int wn   = wv & 1;              // 0..1 h half
  const int l15  = lane & 15;
  const int q    = lane >> 4;           // 0..3

  const int EB = blockIdx.x * 256;

  // ---- staging geometry (chunk-independent)
  const int idx0 = t * 2, idx1 = t * 2 + 1;
  const int h0 = idx0 >> 4, sl0 = idx0 & 15;
  const int h1 = idx1 >> 4, sl1 = idx1 & 15;
  const int lo0 = h0 * CHROW + sl0 * 8, lo1 = h1 * CHROW + sl1 * 8;
  const size_t g0 = (size_t)h0 * KTOT + sl0 * 8, g1 = (size_t)h1 * KTOT + sl1 * 8;

  if constexpr (SECOND){ if (t < 256) s_dst[t] = eidx[E_CNT + EB + t]; }

  // ---- per-mt edge data
  f16x2 apk[4][4];
  long offP[4], offC[4], offA[4];
  uint4 md[4][2];
  #pragma unroll
  for (int mt = 0; mt < 4; ++mt){
    const int e = EB + wm * 64 + mt * 16 + l15;
    const float4* ap = reinterpret_cast<const float4*>(ea + (size_t)e * 8);
    float4 a0 = ap[0], a1 = ap[1];
    apk[mt][0] = pkrtz(a0.x, a0.y);
    apk[mt][1] = pkrtz(a0.z, a0.w);
    apk[mt][2] = pkrtz(a1.x, a1.y);
    apk[mt][3] = pkrtz(a1.z, a1.w);
    if constexpr (!SECOND){
      const long d = eidx[E_CNT + e];
      const long s = eidx[e];
      offP[mt] = d * D_P;
      offC[mt] = s * D_C - D_P;
      offA[mt] = (long)e * D_ADD - (D_P + D_C);
    } else {
      const uint4* mp = reinterpret_cast<const uint4*>(m1in + (size_t)e * 64 + q * 16);
      md[mt][0] = mp[0];
      md[mt][1] = mp[1];
    }
  }

  f32x4 acc[4][2];
  #pragma unroll
  for (int mt = 0; mt < 4; ++mt){
    acc[mt][0] = f32x4{0.f,0.f,0.f,0.f};
    acc[mt][1] = f32x4{0.f,0.f,0.f,0.f};
  }

  float4 xc[4], xn[4];
  const int qf = q * NKS;   // lane's f base

  auto FETCHX = [&](int c, float4* dst){
    if constexpr (!SECOND){
      const int o = qf + 4 * c;
      #pragma unroll
      for (int mt = 0; mt < 4; ++mt){
        const float* p = (o < D_P) ? (x_p + offP[mt] + o)
                       : (o < D_P + D_C) ? (x_c + offC[mt] + o)
                       : (addf + offA[mt] + o);
        dst[mt] = *reinterpret_cast<const float4*>(p);
      }
    }
  };

  // ---- prologue: stage chunk 0, fetch x chunk 0
  uint4 wr0 = *reinterpret_cast<const uint4*>(wt + g0);
  uint4 wr1 = *reinterpret_cast<const uint4*>(wt + g1);
  FETCHX(0, xc);
  *reinterpret_cast<uint4*>(&s_w[0][lo0]) = wr0;
  *reinterpret_cast<uint4*>(&s_w[0][lo1]) = wr1;
  __syncthreads();

  const int wrow = (wn * 32 + l15) * CHROW + q * 8;  // B base (nt=0) in chunk buf

  for (int c = 0; c < NCH; ++c){
    // issue next chunk's global loads early
    if (c + 1 < NCH){
      wr0 = *reinterpret_cast<const uint4*>(wt + g0 + (c + 1) * 128);
      wr1 = *reinterpret_cast<const uint4*>(wt + g1 + (c + 1) * 128);
      FETCHX(c + 1, xn);
    }
    const _Float16* buf = s_w[c & 1];
    #pragma unroll
    for (int ksl = 0; ksl < 4; ++ksl){
      f16x8 Bf[2];
      #pragma unroll
      for (int nt = 0; nt < 2; ++nt)
        Bf[nt] = __builtin_bit_cast(f16x8,
            *reinterpret_cast<const uint4*>(&buf[wrow + nt * 16 * CHROW + ksl * 32]));
      #pragma unroll
      for (int mt = 0; mt < 4; ++mt){
        f16x2 xb;
        if constexpr (!SECOND){
          const float xv = (ksl == 0) ? xc[mt].x : (ksl == 1) ? xc[mt].y
                         : (ksl == 2) ? xc[mt].z : xc[mt].w;
          xb = pkrtz(xv, xv);
        } else {
          const int ks = c * 4 + ksl;
          const unsigned comp = (ks < 8)
              ? ((ks >> 1) == 0 ? md[mt][0].x : (ks >> 1) == 1 ? md[mt][0].y
               : (ks >> 1) == 2 ? md[mt][0].z : md[mt][0].w)
              : (((ks - 8) >> 1) == 0 ? md[mt][1].x : ((ks - 8) >> 1) == 1 ? md[mt][1].y
               : ((ks - 8) >> 1) == 2 ? md[mt][1].z : md[mt][1].w);
          const unsigned v = (ks & 1) ? (comp >> 16) : (comp & 0xffffu);
          xb = __builtin_bit_cast(f16x2, v | (v << 16));
        }
        F16x8U A;
        #pragma unroll
        for (int j = 0; j < 4; ++j) A.h2[j] = xb * apk[mt][j];
        acc[mt][0] = __builtin_amdgcn_mfma_f32_16x16x32_f16(A.v8, Bf[0], acc[mt][0], 0, 0, 0);
        acc[mt][1] = __builtin_amdgcn_mfma_f32_16x16x32_f16(A.v8, Bf[1], acc[mt][1], 0, 0, 0);
      }
    }
    // write next chunk to the other buffer, then one barrier
    if (c + 1 < NCH){
      _Float16* nb = s_w[(c + 1) & 1];
      *reinterpret_cast<uint4*>(&nb[lo0]) = wr0;
      *reinterpret_cast<uint4*>(&nb[lo1]) = wr1;
      #pragma unroll
      for (int mt = 0; mt < 4; ++mt) xc[mt] = xn[mt];
    }
    __syncthreads();
  }

  // ---- epilogue: +bias, SiLU; C/D: col = l15, row = q*4 + r
  float bv[2];
  bv[0] = bias[wn * 32 + l15];
  bv[1] = bias[wn * 32 + 16 + l15];

  #pragma unroll
  for (int mt = 0; mt < 4; ++mt){
    #pragma unroll
    for (int nt = 0; nt < 2; ++nt){
      #pragma unroll
      for (int r = 0; r < 4; ++r){
        float s = silu_f(acc[mt][nt][r] + bv[nt]);
        const int eo = wm * 64 + mt * 16 + q * 4 + r;   // block-local edge
        const int h  = wn * 32 + nt * 16 + l15;
        if constexpr (!SECOND){
          m1out[(size_t)(EB + eo) * 64 + h] = (_Float16)s;
        } else {
          unsafeAtomicAdd(out + (size_t)s_dst[eo] * 144 + 80 + h, s);
        }
      }
    }
  }
}

extern "C" void kernel_launch(void* const* d_in, const int* in_sizes, int n_in,
                              void* d_out, int out_size, void* d_ws, size_t ws_size,
                              hipStream_t stream){
  const float* x_p  = (const float*)d_in[0];
  const float* x_c  = (const float*)d_in[1];
  const int*   eidx = (const int*)d_in[2];
  const float* ea   = (const float*)d_in[3];
  // d_in[4] = batch (unused)
  const float* addf = (const float*)d_in[5];
  const float* W1   = (const float*)d_in[6];
  const float* b1   = (const float*)d_in[7];
  const float* W2   = (const float*)d_in[8];
  const float* b2   = (const float*)d_in[9];
  float* out = (float*)d_out;

  char* ws = (char*)d_ws;
  _Float16* wt1 = (_Float16*)(ws);             // 147456 B
  _Float16* wt2 = (_Float16*)(ws + 163840);    //  65536 B
  _Float16* m1  = (_Float16*)(ws + 262144);    // 16.78 MB (E*64 f16)

  prep_w_kernel<<<(64 * K1 + 64 * K2) / 256, 256, 0, stream>>>(W1, W2, wt1, wt2);
  init_out_kernel<<<(NP_CNT * 36) / 256, 256, 0, stream>>>((const float4*)x_p, (float4*)out);
  msg_gemm_kernel<K1, false><<<E_CNT / 256, 512, 0, stream>>>(
      x_p, x_c, eidx, ea, addf, wt1, b1, nullptr, m1, nullptr);
  msg_gemm_kernel<K2, true><<<E_CNT / 256, 512, 0, stream>>>(
      x_p, x_c, eidx, ea, addf, wt2, b2, (const unsigned short*)m1, nullptr, out);
}

// Round 6
// 107.662 us; speedup vs baseline: 1.2875x; 1.1064x over previous
//
#include <hip/hip_runtime.h>
#include <hip/hip_bf16.h>

// Sizes (fixed by the problem)
#define E_CNT 131072
#define NP_CNT 65536
#define D_P 80
#define D_C 48
#define D_ADD 16
#define K1 1152   // 144*8
#define K2 512    // 64*8

typedef _Float16 f16x8 __attribute__((ext_vector_type(8)));
typedef _Float16 f16x2 __attribute__((ext_vector_type(2)));
typedef float f32x4 __attribute__((ext_vector_type(4)));

union F16x8U { f16x2 h2[4]; f16x8 v8; };

__device__ __forceinline__ float silu_f(float x){
  return x / (1.0f + __expf(-x));
}
__device__ __forceinline__ f16x2 pkrtz(float a, float b){
  return __builtin_bit_cast(f16x2, __builtin_amdgcn_cvt_pkrtz(a, b));
}
__device__ __forceinline__ unsigned pkrtz_u(float a, float b){
  return __builtin_bit_cast(unsigned, __builtin_amdgcn_cvt_pkrtz(a, b));
}

// ---------------------------------------------------------------------------
// K-permutation: logical k = f*8+g; physical k = ks*32 + q*8 + j.
// f(q,ks) = q*NKS + ks (NKS = KTOT/32), g = j. Applied identically to A and B.
// prep_w: Wt[h][ks*32+q*8+j] = W[(q*NKS+ks)*512 + j*64 + h]
// ---------------------------------------------------------------------------
__global__ void prep_w_kernel(const float* __restrict__ W1, const float* __restrict__ W2,
                              _Float16* __restrict__ wt1, _Float16* __restrict__ wt2){
  int id = blockIdx.x * 256 + threadIdx.x;
  if (id < 64 * K1){
    int h = id / K1, k = id - h * K1;
    int ks = k >> 5, rem = k & 31, q = rem >> 3, j = rem & 7;
    wt1[id] = (_Float16)W1[(q * 36 + ks) * 512 + j * 64 + h];
  } else {
    int id2 = id - 64 * K1;
    int h = id2 / K2, k = id2 - h * K2;
    int ks = k >> 5, rem = k & 31, q = rem >> 3, j = rem & 7;
    wt2[id2] = (_Float16)W2[(q * 16 + ks) * 512 + j * 64 + h];
  }
}

// ---------------------------------------------------------------------------
// out[n,0:80] = x_p[n]; out[n,80:144] = 0
// ---------------------------------------------------------------------------
__global__ void init_out_kernel(const float4* __restrict__ xp4, float4* __restrict__ out4){
  int i4 = blockIdx.x * 256 + threadIdx.x;
  int row = i4 / 36;
  int jq = i4 - row * 36;
  float4 z = make_float4(0.f, 0.f, 0.f, 0.f);
  out4[i4] = (jq < 20) ? xp4[row * 20 + jq] : z;
}

// ---------------------------------------------------------------------------
// gather_pack: xg[e][0..143] f16 = concat(x_p[dst], x_c[src], addf[e]).
// 8 lanes per edge; each lane reads whole float4s contiguously within the row
// (128-B segments -> line-efficient random fetch), writes coalesced uint2.
// ---------------------------------------------------------------------------
__global__ __launch_bounds__(256) void gather_pack_kernel(
    const float* __restrict__ x_p, const float* __restrict__ x_c,
    const float* __restrict__ addf, const int* __restrict__ eidx,
    _Float16* __restrict__ xg)
{
  const int t = blockIdx.x * 256 + threadIdx.x;
  const int e = t >> 3;
  const int r = t & 7;
  const int dst = eidx[E_CNT + e];
  const int src = eidx[e];
  const float* pP = x_p  + (size_t)dst * D_P;
  const float* pC = x_c  + (size_t)src * D_C;
  const float* pA = addf + (size_t)e   * D_ADD;
  _Float16* orow = xg + (size_t)e * 144;
  #pragma unroll
  for (int i = 0; i < 5; ++i){
    const int jq = r + 8 * i;          // concat float-quad index 0..35
    if (jq < 36){
      const float* p = (jq < 20) ? (pP + 4 * jq)
                     : (jq < 32) ? (pC + 4 * (jq - 20))
                     : (pA + 4 * (jq - 32));
      float4 v = *reinterpret_cast<const float4*>(p);
      uint2 o;
      o.x = pkrtz_u(v.x, v.y);
      o.y = pkrtz_u(v.z, v.w);
      *reinterpret_cast<uint2*>(orow + 4 * jq) = o;
    }
  }
}

// ---------------------------------------------------------------------------
// Register-A GEMM, chunked-W LDS:
//  - 512 thr = 8 waves = 4 wm x 2 wn; block tile 256 edges x 64 h;
//    wave tile 64 edges x 32 h. Grid = E/256 = 512.
//  - A-frag in registers: lane(l15,q), step ks: x[e, q*NKS+ks]*a[e,0..7].
//    !SECOND: x from packed xg (one uint2 per K128 chunk, sequential edges).
//    SECOND:  x from m1 (fully preloaded, 32 B/lane/mt).
//  - W per K128-chunk in LDS: 2x17 KB double buffer, padded rows, 1 barrier.
// ---------------------------------------------------------------------------
template<int KTOT, bool SECOND>
__global__ __launch_bounds__(512, 4) void msg_gemm_kernel(
    const _Float16* __restrict__ xg,
    const int* __restrict__ eidx, const float* __restrict__ ea,
    const _Float16* __restrict__ wt, const float* __restrict__ bias,
    const unsigned short* __restrict__ m1in,
    _Float16* __restrict__ m1out,
    float* __restrict__ out)
{
  constexpr int NKS = KTOT / 32;        // 36 / 16
  constexpr int NCH = NKS / 4;          // 9 / 4
  constexpr int CHROW = 136;            // padded chunk row (f16)
  __shared__ _Float16 s_w[2][64 * CHROW];
  __shared__ int s_dst[256];

  const int t    = threadIdx.x;
  const int lane = t & 63;
  const int wv   = t >> 6;
  const int wm   = wv >> 1;             // 0..3
  const int wn   = wv & 1;              // 0..1
  const int l15  = lane & 15;
  const int q    = lane >> 4;           // 0..3

  const int EB = blockIdx.x * 256;

  // staging geometry
  const int idx0 = t * 2, idx1 = t * 2 + 1;
  const int h0 = idx0 >> 4, sl0 = idx0 & 15;
  const int h1 = idx1 >> 4, sl1 = idx1 & 15;
  const int lo0 = h0 * CHROW + sl0 * 8, lo1 = h1 * CHROW + sl1 * 8;
  const size_t g0 = (size_t)h0 * KTOT + sl0 * 8, g1 = (size_t)h1 * KTOT + sl1 * 8;

  if constexpr (SECOND){ if (t < 256) s_dst[t] = eidx[E_CNT + EB + t]; }

  // per-mt edge data
  f16x2 apk[4][4];
  int   xb_base[4];
  uint4 md[4][2];
  #pragma unroll
  for (int mt = 0; mt < 4; ++mt){
    const int e = EB + wm * 64 + mt * 16 + l15;
    const float4* ap = reinterpret_cast<const float4*>(ea + (size_t)e * 8);
    float4 a0 = ap[0], a1 = ap[1];
    apk[mt][0] = pkrtz(a0.x, a0.y);
    apk[mt][1] = pkrtz(a0.z, a0.w);
    apk[mt][2] = pkrtz(a1.x, a1.y);
    apk[mt][3] = pkrtz(a1.z, a1.w);
    if constexpr (!SECOND){
      xb_base[mt] = e * 144 + q * NKS;
    } else {
      const uint4* mp = reinterpret_cast<const uint4*>(m1in + (size_t)e * 64 + q * 16);
      md[mt][0] = mp[0];
      md[mt][1] = mp[1];
    }
  }

  f32x4 acc[4][2];
  #pragma unroll
  for (int mt = 0; mt < 4; ++mt){
    acc[mt][0] = f32x4{0.f,0.f,0.f,0.f};
    acc[mt][1] = f32x4{0.f,0.f,0.f,0.f};
  }

  uint2 xc[4], xn[4];

  auto FETCHX = [&](int c, uint2* dstv){
    if constexpr (!SECOND){
      #pragma unroll
      for (int mt = 0; mt < 4; ++mt)
        dstv[mt] = *reinterpret_cast<const uint2*>(xg + xb_base[mt] + 4 * c);
    }
  };

  // prologue
  uint4 wr0 = *reinterpret_cast<const uint4*>(wt + g0);
  uint4 wr1 = *reinterpret_cast<const uint4*>(wt + g1);
  FETCHX(0, xc);
  *reinterpret_cast<uint4*>(&s_w[0][lo0]) = wr0;
  *reinterpret_cast<uint4*>(&s_w[0][lo1]) = wr1;
  __syncthreads();

  const int wrow = (wn * 32 + l15) * CHROW + q * 8;

  for (int c = 0; c < NCH; ++c){
    if (c + 1 < NCH){
      wr0 = *reinterpret_cast<const uint4*>(wt + g0 + (c + 1) * 128);
      wr1 = *reinterpret_cast<const uint4*>(wt + g1 + (c + 1) * 128);
      FETCHX(c + 1, xn);
    }
    const _Float16* buf = s_w[c & 1];
    #pragma unroll
    for (int ksl = 0; ksl < 4; ++ksl){
      f16x8 Bf[2];
      #pragma unroll
      for (int nt = 0; nt < 2; ++nt)
        Bf[nt] = __builtin_bit_cast(f16x8,
            *reinterpret_cast<const uint4*>(&buf[wrow + nt * 16 * CHROW + ksl * 32]));
      #pragma unroll
      for (int mt = 0; mt < 4; ++mt){
        unsigned comp, v;
        if constexpr (!SECOND){
          comp = (ksl < 2) ? xc[mt].x : xc[mt].y;
        } else {
          const int ks = c * 4 + ksl;
          comp = (ks < 8)
              ? ((ks >> 1) == 0 ? md[mt][0].x : (ks >> 1) == 1 ? md[mt][0].y
               : (ks >> 1) == 2 ? md[mt][0].z : md[mt][0].w)
              : (((ks - 8) >> 1) == 0 ? md[mt][1].x : ((ks - 8) >> 1) == 1 ? md[mt][1].y
               : ((ks - 8) >> 1) == 2 ? md[mt][1].z : md[mt][1].w);
        }
        v = (ksl & 1) ? (comp >> 16) : (comp & 0xffffu);
        f16x2 xb = __builtin_bit_cast(f16x2, v | (v << 16));
        F16x8U A;
        #pragma unroll
        for (int j = 0; j < 4; ++j) A.h2[j] = xb * apk[mt][j];
        acc[mt][0] = __builtin_amdgcn_mfma_f32_16x16x32_f16(A.v8, Bf[0], acc[mt][0], 0, 0, 0);
        acc[mt][1] = __builtin_amdgcn_mfma_f32_16x16x32_f16(A.v8, Bf[1], acc[mt][1], 0, 0, 0);
      }
    }
    if (c + 1 < NCH){
      _Float16* nb = s_w[(c + 1) & 1];
      *reinterpret_cast<uint4*>(&nb[lo0]) = wr0;
      *reinterpret_cast<uint4*>(&nb[lo1]) = wr1;
      #pragma unroll
      for (int mt = 0; mt < 4; ++mt) xc[mt] = xn[mt];
    }
    __syncthreads();
  }

  // epilogue: +bias, SiLU; C/D: col = l15, row = q*4 + r
  float bv[2];
  bv[0] = bias[wn * 32 + l15];
  bv[1] = bias[wn * 32 + 16 + l15];

  #pragma unroll
  for (int mt = 0; mt < 4; ++mt){
    #pragma unroll
    for (int nt = 0; nt < 2; ++nt){
      #pragma unroll
      for (int r = 0; r < 4; ++r){
        float s = silu_f(acc[mt][nt][r] + bv[nt]);
        const int eo = wm * 64 + mt * 16 + q * 4 + r;
        const int h  = wn * 32 + nt * 16 + l15;
        if constexpr (!SECOND){
          m1out[(size_t)(EB + eo) * 64 + h] = (_Float16)s;
        } else {
          unsafeAtomicAdd(out + (size_t)s_dst[eo] * 144 + 80 + h, s);
        }
      }
    }
  }
}

extern "C" void kernel_launch(void* const* d_in, const int* in_sizes, int n_in,
                              void* d_out, int out_size, void* d_ws, size_t ws_size,
                              hipStream_t stream){
  const float* x_p  = (const float*)d_in[0];
  const float* x_c  = (const float*)d_in[1];
  const int*   eidx = (const int*)d_in[2];
  const float* ea   = (const float*)d_in[3];
  // d_in[4] = batch (unused)
  const float* addf = (const float*)d_in[5];
  const float* W1   = (const float*)d_in[6];
  const float* b1   = (const float*)d_in[7];
  const float* W2   = (const float*)d_in[8];
  const float* b2   = (const float*)d_in[9];
  float* out = (float*)d_out;

  char* ws = (char*)d_ws;
  _Float16* wt1 = (_Float16*)(ws);              // 147456 B
  _Float16* wt2 = (_Float16*)(ws + 163840);     //  65536 B
  _Float16* m1  = (_Float16*)(ws + 262144);     // 16.78 MB (E*64 f16)
  _Float16* xg  = (_Float16*)(ws + 262144 + (size_t)E_CNT * 64 * 2);  // 37.75 MB (E*144 f16)

  prep_w_kernel<<<(64 * K1 + 64 * K2) / 256, 256, 0, stream>>>(W1, W2, wt1, wt2);
  init_out_kernel<<<(NP_CNT * 36) / 256, 256, 0, stream>>>((const float4*)x_p, (float4*)out);
  gather_pack_kernel<<<E_CNT * 8 / 256, 256, 0, stream>>>(x_p, x_c, addf, eidx, xg);
  msg_gemm_kernel<K1, false><<<E_CNT / 256, 512, 0, stream>>>(
      xg, eidx, ea, wt1, b1, nullptr, m1, nullptr);
  msg_gemm_kernel<K2, true><<<E_CNT / 256, 512, 0, stream>>>(
      xg, eidx, ea, wt2, b2, (const unsigned short*)m1, nullptr, out);
}

// Round 7
// 103.530 us; speedup vs baseline: 1.3389x; 1.0399x over previous
//
#include <hip/hip_runtime.h>
#include <hip/hip_bf16.h>

// Sizes (fixed by the problem)
#define E_CNT 131072
#define NP_CNT 65536
#define D_P 80
#define D_C 48
#define D_ADD 16
#define K1 1152   // 144*8
#define K2 512    // 64*8
#define MAXDEG 32

typedef _Float16 f16x8 __attribute__((ext_vector_type(8)));
typedef _Float16 f16x2 __attribute__((ext_vector_type(2)));
typedef float f32x4 __attribute__((ext_vector_type(4)));

union F16x8U { f16x2 h2[4]; f16x8 v8; };

__device__ __forceinline__ float silu_f(float x){
  return x / (1.0f + __expf(-x));
}
__device__ __forceinline__ f16x2 pkrtz(float a, float b){
  return __builtin_bit_cast(f16x2, __builtin_amdgcn_cvt_pkrtz(a, b));
}
__device__ __forceinline__ unsigned pkrtz_u(float a, float b){
  return __builtin_bit_cast(unsigned, __builtin_amdgcn_cvt_pkrtz(a, b));
}

// ---------------------------------------------------------------------------
// K-permutation: logical k = f*8+g; physical k = ks*32 + q*8 + j.
// f(q,ks) = q*NKS + ks (NKS = KTOT/32), g = j. Applied identically to A and B.
// ---------------------------------------------------------------------------
__global__ void prep_w_kernel(const float* __restrict__ W1, const float* __restrict__ W2,
                              _Float16* __restrict__ wt1, _Float16* __restrict__ wt2){
  int id = blockIdx.x * 256 + threadIdx.x;
  if (id < 64 * K1){
    int h = id / K1, k = id - h * K1;
    int ks = k >> 5, rem = k & 31, q = rem >> 3, j = rem & 7;
    wt1[id] = (_Float16)W1[(q * 36 + ks) * 512 + j * 64 + h];
  } else {
    int id2 = id - 64 * K1;
    int h = id2 / K2, k = id2 - h * K2;
    int ks = k >> 5, rem = k & 31, q = rem >> 3, j = rem & 7;
    wt2[id2] = (_Float16)W2[(q * 16 + ks) * 512 + j * 64 + h];
  }
}

// ---------------------------------------------------------------------------
// CSR-lite: zero counters, then slot-fill (degree-bounded table, no sort/scan)
// ---------------------------------------------------------------------------
__global__ void zero_cnt_kernel(int* __restrict__ cnt){
  cnt[blockIdx.x * 256 + threadIdx.x] = 0;
}
__global__ void fill_slots_kernel(const int* __restrict__ eidx,
                                  int* __restrict__ cnt, int* __restrict__ slots){
  const int e = blockIdx.x * 256 + threadIdx.x;
  const int d = eidx[E_CNT + e];
  const int p = atomicAdd(&cnt[d], 1);
  if (p < MAXDEG) slots[d * MAXDEG + p] = e;
}

// ---------------------------------------------------------------------------
// gather_pack: xg[e][0..143] f16 = concat(x_p[dst], x_c[src], addf[e]).
// 8 lanes per edge; line-efficient random fetch, coalesced packed write.
// ---------------------------------------------------------------------------
__global__ __launch_bounds__(256) void gather_pack_kernel(
    const float* __restrict__ x_p, const float* __restrict__ x_c,
    const float* __restrict__ addf, const int* __restrict__ eidx,
    _Float16* __restrict__ xg)
{
  const int t = blockIdx.x * 256 + threadIdx.x;
  const int e = t >> 3;
  const int r = t & 7;
  const int dst = eidx[E_CNT + e];
  const int src = eidx[e];
  const float* pP = x_p  + (size_t)dst * D_P;
  const float* pC = x_c  + (size_t)src * D_C;
  const float* pA = addf + (size_t)e   * D_ADD;
  _Float16* orow = xg + (size_t)e * 144;
  #pragma unroll
  for (int i = 0; i < 5; ++i){
    const int jq = r + 8 * i;          // concat float-quad index 0..35
    if (jq < 36){
      const float* p = (jq < 20) ? (pP + 4 * jq)
                     : (jq < 32) ? (pC + 4 * (jq - 20))
                     : (pA + 4 * (jq - 32));
      float4 v = *reinterpret_cast<const float4*>(p);
      uint2 o;
      o.x = pkrtz_u(v.x, v.y);
      o.y = pkrtz_u(v.z, v.w);
      *reinterpret_cast<uint2*>(orow + 4 * jq) = o;
    }
  }
}

// ---------------------------------------------------------------------------
// Register-A GEMM, chunked-W LDS. Both layers write coalesced f16 rows:
// layer1 xg->m1, layer2 m1->m2. No atomics, no scatter.
// 512 thr = 8 waves = 4 wm x 2 wn; block tile 256 edges x 64 h.
// ---------------------------------------------------------------------------
template<int KTOT, bool SECOND>
__global__ __launch_bounds__(512, 4) void msg_gemm_kernel(
    const _Float16* __restrict__ xg,
    const float* __restrict__ ea,
    const _Float16* __restrict__ wt, const float* __restrict__ bias,
    const unsigned short* __restrict__ m1in,
    _Float16* __restrict__ mout)
{
  constexpr int NKS = KTOT / 32;        // 36 / 16
  constexpr int NCH = NKS / 4;          // 9 / 4
  constexpr int CHROW = 136;            // padded chunk row (f16)
  __shared__ _Float16 s_w[2][64 * CHROW];

  const int t    = threadIdx.x;
  const int lane = t & 63;
  const int wv   = t >> 6;
  const int wm   = wv >> 1;             // 0..3
  const int wn   = wv & 1;              // 0..1
  const int l15  = lane & 15;
  const int q    = lane >> 4;           // 0..3

  const int EB = blockIdx.x * 256;

  // staging geometry
  const int idx0 = t * 2, idx1 = t * 2 + 1;
  const int h0 = idx0 >> 4, sl0 = idx0 & 15;
  const int h1 = idx1 >> 4, sl1 = idx1 & 15;
  const int lo0 = h0 * CHROW + sl0 * 8, lo1 = h1 * CHROW + sl1 * 8;
  const size_t g0 = (size_t)h0 * KTOT + sl0 * 8, g1 = (size_t)h1 * KTOT + sl1 * 8;

  // per-mt edge data
  f16x2 apk[4][4];
  int   xb_base[4];
  uint4 md[4][2];
  #pragma unroll
  for (int mt = 0; mt < 4; ++mt){
    const int e = EB + wm * 64 + mt * 16 + l15;
    const float4* ap = reinterpret_cast<const float4*>(ea + (size_t)e * 8);
    float4 a0 = ap[0], a1 = ap[1];
    apk[mt][0] = pkrtz(a0.x, a0.y);
    apk[mt][1] = pkrtz(a0.z, a0.w);
    apk[mt][2] = pkrtz(a1.x, a1.y);
    apk[mt][3] = pkrtz(a1.z, a1.w);
    if constexpr (!SECOND){
      xb_base[mt] = e * 144 + q * NKS;
    } else {
      const uint4* mp = reinterpret_cast<const uint4*>(m1in + (size_t)e * 64 + q * 16);
      md[mt][0] = mp[0];
      md[mt][1] = mp[1];
    }
  }

  f32x4 acc[4][2];
  #pragma unroll
  for (int mt = 0; mt < 4; ++mt){
    acc[mt][0] = f32x4{0.f,0.f,0.f,0.f};
    acc[mt][1] = f32x4{0.f,0.f,0.f,0.f};
  }

  uint2 xc[4], xn[4];

  auto FETCHX = [&](int c, uint2* dstv){
    if constexpr (!SECOND){
      #pragma unroll
      for (int mt = 0; mt < 4; ++mt)
        dstv[mt] = *reinterpret_cast<const uint2*>(xg + xb_base[mt] + 4 * c);
    }
  };

  // prologue
  uint4 wr0 = *reinterpret_cast<const uint4*>(wt + g0);
  uint4 wr1 = *reinterpret_cast<const uint4*>(wt + g1);
  FETCHX(0, xc);
  *reinterpret_cast<uint4*>(&s_w[0][lo0]) = wr0;
  *reinterpret_cast<uint4*>(&s_w[0][lo1]) = wr1;
  __syncthreads();

  const int wrow = (wn * 32 + l15) * CHROW + q * 8;

  for (int c = 0; c < NCH; ++c){
    if (c + 1 < NCH){
      wr0 = *reinterpret_cast<const uint4*>(wt + g0 + (c + 1) * 128);
      wr1 = *reinterpret_cast<const uint4*>(wt + g1 + (c + 1) * 128);
      FETCHX(c + 1, xn);
    }
    const _Float16* buf = s_w[c & 1];
    #pragma unroll
    for (int ksl = 0; ksl < 4; ++ksl){
      f16x8 Bf[2];
      #pragma unroll
      for (int nt = 0; nt < 2; ++nt)
        Bf[nt] = __builtin_bit_cast(f16x8,
            *reinterpret_cast<const uint4*>(&buf[wrow + nt * 16 * CHROW + ksl * 32]));
      #pragma unroll
      for (int mt = 0; mt < 4; ++mt){
        unsigned comp, v;
        if constexpr (!SECOND){
          comp = (ksl < 2) ? xc[mt].x : xc[mt].y;
        } else {
          const int ks = c * 4 + ksl;
          comp = (ks < 8)
              ? ((ks >> 1) == 0 ? md[mt][0].x : (ks >> 1) == 1 ? md[mt][0].y
               : (ks >> 1) == 2 ? md[mt][0].z : md[mt][0].w)
              : (((ks - 8) >> 1) == 0 ? md[mt][1].x : ((ks - 8) >> 1) == 1 ? md[mt][1].y
               : ((ks - 8) >> 1) == 2 ? md[mt][1].z : md[mt][1].w);
        }
        v = (ksl & 1) ? (comp >> 16) : (comp & 0xffffu);
        f16x2 xb = __builtin_bit_cast(f16x2, v | (v << 16));
        F16x8U A;
        #pragma unroll
        for (int j = 0; j < 4; ++j) A.h2[j] = xb * apk[mt][j];
        acc[mt][0] = __builtin_amdgcn_mfma_f32_16x16x32_f16(A.v8, Bf[0], acc[mt][0], 0, 0, 0);
        acc[mt][1] = __builtin_amdgcn_mfma_f32_16x16x32_f16(A.v8, Bf[1], acc[mt][1], 0, 0, 0);
      }
    }
    if (c + 1 < NCH){
      _Float16* nb = s_w[(c + 1) & 1];
      *reinterpret_cast<uint4*>(&nb[lo0]) = wr0;
      *reinterpret_cast<uint4*>(&nb[lo1]) = wr1;
      #pragma unroll
      for (int mt = 0; mt < 4; ++mt) xc[mt] = xn[mt];
    }
    __syncthreads();
  }

  // epilogue: +bias, SiLU, coalesced f16 store. C/D: col=l15, row=q*4+r
  float bv[2];
  bv[0] = bias[wn * 32 + l15];
  bv[1] = bias[wn * 32 + 16 + l15];

  #pragma unroll
  for (int mt = 0; mt < 4; ++mt){
    #pragma unroll
    for (int nt = 0; nt < 2; ++nt){
      #pragma unroll
      for (int r = 0; r < 4; ++r){
        float s = silu_f(acc[mt][nt][r] + bv[nt]);
        const int eo = wm * 64 + mt * 16 + q * 4 + r;
        const int h  = wn * 32 + nt * 16 + l15;
        mout[(size_t)(EB + eo) * 64 + h] = (_Float16)s;
      }
    }
  }
}

// ---------------------------------------------------------------------------
// combine: out[n] = concat(x_p[n], sum_{e in slots[n]} m2[e])  (8 lanes/node)
// ---------------------------------------------------------------------------
__global__ __launch_bounds__(256) void combine_kernel(
    const float* __restrict__ x_p, const int* __restrict__ cnt,
    const int* __restrict__ slots, const _Float16* __restrict__ m2,
    float* __restrict__ out)
{
  const int gid = blockIdx.x * 256 + threadIdx.x;
  const int n = gid >> 3;
  const int r = gid & 7;
  const float* ps = x_p + (size_t)n * D_P;
  float* po = out + (size_t)n * 144;
  #pragma unroll
  for (int i = 0; i < 3; ++i){
    const int j4 = r + 8 * i;
    if (j4 < 20)
      *reinterpret_cast<float4*>(po + 4 * j4) = *reinterpret_cast<const float4*>(ps + 4 * j4);
  }
  float s[8] = {0.f,0.f,0.f,0.f,0.f,0.f,0.f,0.f};
  int d = cnt[n];
  if (d > MAXDEG) d = MAXDEG;
  for (int j = 0; j < d; ++j){
    const int eid = slots[n * MAXDEG + j];
    const uint4 mv = *reinterpret_cast<const uint4*>(m2 + (size_t)eid * 64 + r * 8);
    f16x8 mh = __builtin_bit_cast(f16x8, mv);
    #pragma unroll
    for (int k = 0; k < 8; ++k) s[k] += (float)mh[k];
  }
  float4 o0 = make_float4(s[0], s[1], s[2], s[3]);
  float4 o1 = make_float4(s[4], s[5], s[6], s[7]);
  *reinterpret_cast<float4*>(po + 80 + r * 8)     = o0;
  *reinterpret_cast<float4*>(po + 80 + r * 8 + 4) = o1;
}

extern "C" void kernel_launch(void* const* d_in, const int* in_sizes, int n_in,
                              void* d_out, int out_size, void* d_ws, size_t ws_size,
                              hipStream_t stream){
  const float* x_p  = (const float*)d_in[0];
  const float* x_c  = (const float*)d_in[1];
  const int*   eidx = (const int*)d_in[2];
  const float* ea   = (const float*)d_in[3];
  // d_in[4] = batch (unused)
  const float* addf = (const float*)d_in[5];
  const float* W1   = (const float*)d_in[6];
  const float* b1   = (const float*)d_in[7];
  const float* W2   = (const float*)d_in[8];
  const float* b2   = (const float*)d_in[9];
  float* out = (float*)d_out;

  char* ws = (char*)d_ws;
  _Float16* wt1 = (_Float16*)(ws);              // 147456 B
  _Float16* wt2 = (_Float16*)(ws + 163840);     //  65536 B
  _Float16* m1  = (_Float16*)(ws + 262144);                                  // 16.78 MB
  _Float16* xg  = (_Float16*)(ws + 262144 + (size_t)E_CNT * 64 * 2);         // 37.75 MB
  _Float16* m2  = (_Float16*)(ws + 262144 + (size_t)E_CNT * (64 + 144) * 2); // 16.78 MB
  int* cnt   = (int*)(ws + 262144 + (size_t)E_CNT * (64 + 144 + 64) * 2);    // 256 KB
  int* slots = (int*)((char*)cnt + (size_t)NP_CNT * 4);                      // 8 MB

  prep_w_kernel<<<(64 * K1 + 64 * K2) / 256, 256, 0, stream>>>(W1, W2, wt1, wt2);
  zero_cnt_kernel<<<NP_CNT / 256, 256, 0, stream>>>(cnt);
  fill_slots_kernel<<<E_CNT / 256, 256, 0, stream>>>(eidx, cnt, slots);
  gather_pack_kernel<<<E_CNT * 8 / 256, 256, 0, stream>>>(x_p, x_c, addf, eidx, xg);
  msg_gemm_kernel<K1, false><<<E_CNT / 256, 512, 0, stream>>>(
      xg, ea, wt1, b1, nullptr, m1);
  msg_gemm_kernel<K2, true><<<E_CNT / 256, 512, 0, stream>>>(
      xg, ea, wt2, b2, (const unsigned short*)m1, m2);
  combine_kernel<<<NP_CNT * 8 / 256, 256, 0, stream>>>(x_p, cnt, slots, m2, out);
}

// Round 8
// 92.839 us; speedup vs baseline: 1.4931x; 1.1152x over previous
//
#include <hip/hip_runtime.h>
#include <hip/hip_bf16.h>

// Sizes (fixed by the problem)
#define E_CNT 131072
#define NP_CNT 65536
#define D_P 80
#define D_C 48
#define D_ADD 16
#define K1 1152   // 144*8
#define K2 512    // 64*8
#define MAXDEG 32

typedef _Float16 f16x8 __attribute__((ext_vector_type(8)));
typedef _Float16 f16x2 __attribute__((ext_vector_type(2)));
typedef float f32x4 __attribute__((ext_vector_type(4)));

union F16x8U { f16x2 h2[4]; f16x8 v8; };

__device__ __forceinline__ float silu_f(float x){
  return x / (1.0f + __expf(-x));
}
__device__ __forceinline__ f16x2 pkrtz(float a, float b){
  return __builtin_bit_cast(f16x2, __builtin_amdgcn_cvt_pkrtz(a, b));
}

// ---------------------------------------------------------------------------
// K-permutation: logical k = f*8+g; physical k = ks*32 + q*8 + j.
// f(q,ks) = q*NKS + ks (NKS = KTOT/32), g = j. Applied identically to A and B.
// ---------------------------------------------------------------------------
__global__ void prep_w_kernel(const float* __restrict__ W1, const float* __restrict__ W2,
                              _Float16* __restrict__ wt1, _Float16* __restrict__ wt2){
  int id = blockIdx.x * 256 + threadIdx.x;
  if (id < 64 * K1){
    int h = id / K1, k = id - h * K1;
    int ks = k >> 5, rem = k & 31, q = rem >> 3, j = rem & 7;
    wt1[id] = (_Float16)W1[(q * 36 + ks) * 512 + j * 64 + h];
  } else {
    int id2 = id - 64 * K1;
    int h = id2 / K2, k = id2 - h * K2;
    int ks = k >> 5, rem = k & 31, q = rem >> 3, j = rem & 7;
    wt2[id2] = (_Float16)W2[(q * 16 + ks) * 512 + j * 64 + h];
  }
}

// ---------------------------------------------------------------------------
// CSR build: zero, slot-fill, 3-step scan -> off[] and perm[] (edges by dst)
// ---------------------------------------------------------------------------
__global__ void zero_cnt_kernel(int* __restrict__ cnt, int* __restrict__ bsum){
  const int gid = blockIdx.x * 256 + threadIdx.x;
  if (gid < NP_CNT) cnt[gid] = 0;
  else bsum[gid - NP_CNT] = 0;
}
__global__ void fill_slots_kernel(const int* __restrict__ eidx,
                                  int* __restrict__ cnt, int* __restrict__ slots){
  const int e = blockIdx.x * 256 + threadIdx.x;
  const int d = eidx[E_CNT + e];
  const int p = atomicAdd(&cnt[d], 1);
  if (p < MAXDEG) slots[d * MAXDEG + p] = e;
}
__global__ void scanA_kernel(const int* __restrict__ cnt, int* __restrict__ bsum){
  const int t = threadIdx.x;
  int v = min(cnt[blockIdx.x * 256 + t], MAXDEG);
  #pragma unroll
  for (int o = 32; o; o >>= 1) v += __shfl_down(v, o);
  __shared__ int s[4];
  if ((t & 63) == 0) s[t >> 6] = v;
  __syncthreads();
  if (t == 0) bsum[blockIdx.x] = s[0] + s[1] + s[2] + s[3];
}
__global__ void scanB_kernel(const int* __restrict__ bsum, int* __restrict__ boff){
  __shared__ int s[256];
  const int t = threadIdx.x;
  const int v = bsum[t];
  s[t] = v; __syncthreads();
  for (int o = 1; o < 256; o <<= 1){
    int x = (t >= o) ? s[t - o] : 0;
    __syncthreads();
    s[t] += x;
    __syncthreads();
  }
  boff[t] = s[t] - v;
}
__global__ void scanC_emit_kernel(const int* __restrict__ cnt, const int* __restrict__ slots,
                                  const int* __restrict__ boff,
                                  int* __restrict__ off, int* __restrict__ perm){
  __shared__ int s[256];
  const int t = threadIdx.x;
  const int n = blockIdx.x * 256 + t;
  const int v = min(cnt[n], MAXDEG);
  s[t] = v; __syncthreads();
  for (int o = 1; o < 256; o <<= 1){
    int x = (t >= o) ? s[t - o] : 0;
    __syncthreads();
    s[t] += x;
    __syncthreads();
  }
  const int o0 = boff[blockIdx.x] + s[t] - v;
  off[n] = o0;
  for (int j = 0; j < v; ++j) perm[o0 + j] = slots[n * MAXDEG + j];
}

// ---------------------------------------------------------------------------
// Fused 2-layer GEMM over permuted edges.
// 512 thr = 8 waves = 4 wm x 2 wn; block tile 256 edges x 64 h.
// Layer 1: x gathered direct from global (float4/lane/chunk; perm => x_p
// streams). W1 in chunked double-buffered LDS. m1 -> LDS [256][72] f16.
// Layer 2: A from LDS m1; W2 same chunk pipeline; m2p written coalesced
// in PERM order (combine reads contiguous rows per node).
// ---------------------------------------------------------------------------
__global__ __launch_bounds__(512, 4) void fused_gemm_kernel(
    const float* __restrict__ x_p, const float* __restrict__ x_c,
    const int* __restrict__ eidx, const float* __restrict__ ea,
    const float* __restrict__ addf, const int* __restrict__ perm,
    const _Float16* __restrict__ wt1, const float* __restrict__ b1,
    const _Float16* __restrict__ wt2, const float* __restrict__ b2,
    _Float16* __restrict__ m2p)
{
  constexpr int CHROW = 136;            // padded chunk row (f16)
  __shared__ _Float16 s_w[2][64 * CHROW];   // 34.8 KB
  __shared__ _Float16 s_m1[256 * 72];       // 36.9 KB

  const int t    = threadIdx.x;
  const int lane = t & 63;
  const int wv   = t >> 6;
  const int wm   = wv >> 1;             // 0..3 edge quarter
  const int wn   = wv & 1;              // 0..1 h half
  const int l15  = lane & 15;
  const int q    = lane >> 4;           // 0..3

  const int EB = blockIdx.x * 256;      // position base (perm space)

  // staging geometry (shared by both layers)
  const int idx0 = t * 2, idx1 = t * 2 + 1;
  const int h0 = idx0 >> 4, sl0 = idx0 & 15;
  const int h1 = idx1 >> 4, sl1 = idx1 & 15;
  const int lo0 = h0 * CHROW + sl0 * 8, lo1 = h1 * CHROW + sl1 * 8;
  const size_t g0_1 = (size_t)h0 * K1 + sl0 * 8, g1_1 = (size_t)h1 * K1 + sl1 * 8;
  const size_t g0_2 = (size_t)h0 * K2 + sl0 * 8, g1_2 = (size_t)h1 * K2 + sl1 * 8;

  // per-mt edge data (perm'd)
  f16x2 apk[4][4];
  int offP[4], offC[4], offA[4];
  #pragma unroll
  for (int mt = 0; mt < 4; ++mt){
    const int e = perm[EB + wm * 64 + mt * 16 + l15] & (E_CNT - 1);
    const float4* ap = reinterpret_cast<const float4*>(ea + (size_t)e * 8);
    float4 a0 = ap[0], a1 = ap[1];
    apk[mt][0] = pkrtz(a0.x, a0.y);
    apk[mt][1] = pkrtz(a0.z, a0.w);
    apk[mt][2] = pkrtz(a1.x, a1.y);
    apk[mt][3] = pkrtz(a1.z, a1.w);
    const int dn = eidx[E_CNT + e];
    const int sn = eidx[e];
    offP[mt] = dn * D_P;
    offC[mt] = sn * D_C - D_P;
    offA[mt] = e * D_ADD - (D_P + D_C);
  }

  f32x4 acc[4][2];
  #pragma unroll
  for (int mt = 0; mt < 4; ++mt){
    acc[mt][0] = f32x4{0.f,0.f,0.f,0.f};
    acc[mt][1] = f32x4{0.f,0.f,0.f,0.f};
  }

  float4 xc[4], xn[4];
  auto FETCHX = [&](int c, float4* dst){
    const int o = q * 36 + 4 * c;
    #pragma unroll
    for (int mt = 0; mt < 4; ++mt){
      const float* p = (o < D_P) ? (x_p + offP[mt] + o)
                     : (o < D_P + D_C) ? (x_c + offC[mt] + o)
                     : (addf + offA[mt] + o);
      dst[mt] = *reinterpret_cast<const float4*>(p);
    }
  };

  const int wrow = (wn * 32 + l15) * CHROW + q * 8;

  // ================= LAYER 1 (9 chunks of K=128) =================
  uint4 wr0 = *reinterpret_cast<const uint4*>(wt1 + g0_1);
  uint4 wr1 = *reinterpret_cast<const uint4*>(wt1 + g1_1);
  FETCHX(0, xc);
  *reinterpret_cast<uint4*>(&s_w[0][lo0]) = wr0;
  *reinterpret_cast<uint4*>(&s_w[0][lo1]) = wr1;
  __syncthreads();

  for (int c = 0; c < 9; ++c){
    if (c < 8){
      wr0 = *reinterpret_cast<const uint4*>(wt1 + g0_1 + (c + 1) * 128);
      wr1 = *reinterpret_cast<const uint4*>(wt1 + g1_1 + (c + 1) * 128);
      FETCHX(c + 1, xn);
    }
    const _Float16* buf = s_w[c & 1];
    #pragma unroll
    for (int ksl = 0; ksl < 4; ++ksl){
      f16x8 Bf[2];
      #pragma unroll
      for (int nt = 0; nt < 2; ++nt)
        Bf[nt] = __builtin_bit_cast(f16x8,
            *reinterpret_cast<const uint4*>(&buf[wrow + nt * 16 * CHROW + ksl * 32]));
      #pragma unroll
      for (int mt = 0; mt < 4; ++mt){
        const float xv = (ksl == 0) ? xc[mt].x : (ksl == 1) ? xc[mt].y
                       : (ksl == 2) ? xc[mt].z : xc[mt].w;
        f16x2 xb = pkrtz(xv, xv);
        F16x8U A;
        #pragma unroll
        for (int j = 0; j < 4; ++j) A.h2[j] = xb * apk[mt][j];
        acc[mt][0] = __builtin_amdgcn_mfma_f32_16x16x32_f16(A.v8, Bf[0], acc[mt][0], 0, 0, 0);
        acc[mt][1] = __builtin_amdgcn_mfma_f32_16x16x32_f16(A.v8, Bf[1], acc[mt][1], 0, 0, 0);
      }
    }
    if (c < 8){
      _Float16* nb = s_w[(c + 1) & 1];
      *reinterpret_cast<uint4*>(&nb[lo0]) = wr0;
      *reinterpret_cast<uint4*>(&nb[lo1]) = wr1;
      #pragma unroll
      for (int mt = 0; mt < 4; ++mt) xc[mt] = xn[mt];
    }
    __syncthreads();
  }

  // issue layer-2 chunk-0 W loads early (hide under epilogue-1)
  wr0 = *reinterpret_cast<const uint4*>(wt2 + g0_2);
  wr1 = *reinterpret_cast<const uint4*>(wt2 + g1_2);

  // ---- epilogue 1: +b1, SiLU -> s_m1 (f16). C/D: col=l15, row=q*4+r
  {
    float bv[2];
    bv[0] = b1[wn * 32 + l15];
    bv[1] = b1[wn * 32 + 16 + l15];
    #pragma unroll
    for (int mt = 0; mt < 4; ++mt){
      #pragma unroll
      for (int nt = 0; nt < 2; ++nt){
        #pragma unroll
        for (int r = 0; r < 4; ++r){
          float s = silu_f(acc[mt][nt][r] + bv[nt]);
          const int eo = wm * 64 + mt * 16 + q * 4 + r;
          const int h  = wn * 32 + nt * 16 + l15;
          s_m1[eo * 72 + h] = (_Float16)s;
        }
      }
    }
  }
  __syncthreads();

  // ---- preload A-data for layer 2 from LDS m1; stage W2 chunk 0
  uint4 md[4][2];
  #pragma unroll
  for (int mt = 0; mt < 4; ++mt){
    const int eo = wm * 64 + mt * 16 + l15;
    const uint4* mp = reinterpret_cast<const uint4*>(&s_m1[eo * 72 + q * 16]);
    md[mt][0] = mp[0];
    md[mt][1] = mp[1];
  }
  *reinterpret_cast<uint4*>(&s_w[0][lo0]) = wr0;
  *reinterpret_cast<uint4*>(&s_w[0][lo1]) = wr1;
  #pragma unroll
  for (int mt = 0; mt < 4; ++mt){
    acc[mt][0] = f32x4{0.f,0.f,0.f,0.f};
    acc[mt][1] = f32x4{0.f,0.f,0.f,0.f};
  }
  __syncthreads();

  // ================= LAYER 2 (4 chunks of K=128) =================
  for (int c = 0; c < 4; ++c){
    if (c < 3){
      wr0 = *reinterpret_cast<const uint4*>(wt2 + g0_2 + (c + 1) * 128);
      wr1 = *reinterpret_cast<const uint4*>(wt2 + g1_2 + (c + 1) * 128);
    }
    const _Float16* buf = s_w[c & 1];
    #pragma unroll
    for (int ksl = 0; ksl < 4; ++ksl){
      f16x8 Bf[2];
      #pragma unroll
      for (int nt = 0; nt < 2; ++nt)
        Bf[nt] = __builtin_bit_cast(f16x8,
            *reinterpret_cast<const uint4*>(&buf[wrow + nt * 16 * CHROW + ksl * 32]));
      const int ks = c * 4 + ksl;
      #pragma unroll
      for (int mt = 0; mt < 4; ++mt){
        const unsigned comp = (ks < 8)
            ? ((ks >> 1) == 0 ? md[mt][0].x : (ks >> 1) == 1 ? md[mt][0].y
             : (ks >> 1) == 2 ? md[mt][0].z : md[mt][0].w)
            : (((ks - 8) >> 1) == 0 ? md[mt][1].x : ((ks - 8) >> 1) == 1 ? md[mt][1].y
             : ((ks - 8) >> 1) == 2 ? md[mt][1].z : md[mt][1].w);
        const unsigned v = (ks & 1) ? (comp >> 16) : (comp & 0xffffu);
        f16x2 xb = __builtin_bit_cast(f16x2, v | (v << 16));
        F16x8U A;
        #pragma unroll
        for (int j = 0; j < 4; ++j) A.h2[j] = xb * apk[mt][j];
        acc[mt][0] = __builtin_amdgcn_mfma_f32_16x16x32_f16(A.v8, Bf[0], acc[mt][0], 0, 0, 0);
        acc[mt][1] = __builtin_amdgcn_mfma_f32_16x16x32_f16(A.v8, Bf[1], acc[mt][1], 0, 0, 0);
      }
    }
    if (c < 3){
      _Float16* nb = s_w[(c + 1) & 1];
      *reinterpret_cast<uint4*>(&nb[lo0]) = wr0;
      *reinterpret_cast<uint4*>(&nb[lo1]) = wr1;
    }
    __syncthreads();
  }

  // ---- epilogue 2: +b2, SiLU -> m2p (perm order, coalesced)
  {
    float bv[2];
    bv[0] = b2[wn * 32 + l15];
    bv[1] = b2[wn * 32 + 16 + l15];
    #pragma unroll
    for (int mt = 0; mt < 4; ++mt){
      #pragma unroll
      for (int nt = 0; nt < 2; ++nt){
        #pragma unroll
        for (int r = 0; r < 4; ++r){
          float s = silu_f(acc[mt][nt][r] + bv[nt]);
          const int eo = wm * 64 + mt * 16 + q * 4 + r;
          const int h  = wn * 32 + nt * 16 + l15;
          m2p[(size_t)(EB + eo) * 64 + h] = (_Float16)s;
        }
      }
    }
  }
}

// ---------------------------------------------------------------------------
// combine: out[n] = concat(x_p[n], sum_{j<d} m2p[off[n]+j])   (8 lanes/node)
// m2p rows for a node are CONTIGUOUS (perm order) -> streaming reads.
// ---------------------------------------------------------------------------
__global__ __launch_bounds__(256) void combine_kernel(
    const float* __restrict__ x_p, const int* __restrict__ cnt,
    const int* __restrict__ off, const _Float16* __restrict__ m2p,
    float* __restrict__ out)
{
  const int gid = blockIdx.x * 256 + threadIdx.x;
  const int n = gid >> 3;
  const int r = gid & 7;
  const float* ps = x_p + (size_t)n * D_P;
  float* po = out + (size_t)n * 144;
  #pragma unroll
  for (int i = 0; i < 3; ++i){
    const int j4 = r + 8 * i;
    if (j4 < 20)
      *reinterpret_cast<float4*>(po + 4 * j4) = *reinterpret_cast<const float4*>(ps + 4 * j4);
  }
  float s[8] = {0.f,0.f,0.f,0.f,0.f,0.f,0.f,0.f};
  const int o0 = off[n];
  const int d  = min(cnt[n], MAXDEG);
  for (int j = 0; j < d; ++j){
    const uint4 mv = *reinterpret_cast<const uint4*>(m2p + (size_t)(o0 + j) * 64 + r * 8);
    f16x8 mh = __builtin_bit_cast(f16x8, mv);
    #pragma unroll
    for (int k = 0; k < 8; ++k) s[k] += (float)mh[k];
  }
  float4 o0v = make_float4(s[0], s[1], s[2], s[3]);
  float4 o1v = make_float4(s[4], s[5], s[6], s[7]);
  *reinterpret_cast<float4*>(po + 80 + r * 8)     = o0v;
  *reinterpret_cast<float4*>(po + 80 + r * 8 + 4) = o1v;
}

extern "C" void kernel_launch(void* const* d_in, const int* in_sizes, int n_in,
                              void* d_out, int out_size, void* d_ws, size_t ws_size,
                              hipStream_t stream){
  const float* x_p  = (const float*)d_in[0];
  const float* x_c  = (const float*)d_in[1];
  const int*   eidx = (const int*)d_in[2];
  const float* ea   = (const float*)d_in[3];
  // d_in[4] = batch (unused)
  const float* addf = (const float*)d_in[5];
  const float* W1   = (const float*)d_in[6];
  const float* b1   = (const float*)d_in[7];
  const float* W2   = (const float*)d_in[8];
  const float* b2   = (const float*)d_in[9];
  float* out = (float*)d_out;

  char* ws = (char*)d_ws;
  _Float16* wt1 = (_Float16*)(ws);                 // 147456 B
  _Float16* wt2 = (_Float16*)(ws + 163840);        //  65536 B
  int* cnt   = (int*)(ws + 262144);                // 256 KB
  int* bsum  = (int*)(ws + 524288);                // 1 KB
  int* boff  = (int*)(ws + 525312);                // 1 KB
  int* off   = (int*)(ws + 526336);                // 256 KB
  int* slots = (int*)(ws + 788480);                // 8 MB
  int* perm  = (int*)(ws + 9177088);               // 512 KB
  _Float16* m2p = (_Float16*)(ws + 9701376);       // 16.78 MB

  prep_w_kernel<<<(64 * K1 + 64 * K2) / 256, 256, 0, stream>>>(W1, W2, wt1, wt2);
  zero_cnt_kernel<<<(NP_CNT + 256) / 256, 256, 0, stream>>>(cnt, bsum);
  fill_slots_kernel<<<E_CNT / 256, 256, 0, stream>>>(eidx, cnt, slots);
  scanA_kernel<<<NP_CNT / 256, 256, 0, stream>>>(cnt, bsum);
  scanB_kernel<<<1, 256, 0, stream>>>(bsum, boff);
  scanC_emit_kernel<<<NP_CNT / 256, 256, 0, stream>>>(cnt, slots, boff, off, perm);
  fused_gemm_kernel<<<E_CNT / 256, 512, 0, stream>>>(
      x_p, x_c, eidx, ea, addf, perm, wt1, b1, wt2, b2, m2p);
  combine_kernel<<<NP_CNT * 8 / 256, 256, 0, stream>>>(x_p, cnt, off, m2p, out);
}